// Round 4
// baseline (1048.291 us; speedup 1.0000x reference)
//
#include <hip/hip_runtime.h>
#include <stdint.h>
#include <stddef.h>

// ---------------------------------------------------------------------------
// Aligner (fp32 I/O), algebraically collapsed:
//   S = ex.eo^T  ==  X G O^T + (X r)1^T + 1(O r)^T + b.b   with G=W^T W, r=W^T b
//   Row-constant terms cancel in softmax  =>  S_eff = X G O^T + 1 (O r)^T
//   out = softmax(S_eff) @ O
// Precision: all GEMM operands in fp16 (single pass). dS std ~0.011 vs
// softmax gap scale ~7 -> out err ~0.03.  S fp32, stats fp32, out fp32.
// B=8, L=2048, D=1024.  Workspace <= 40 MiB (tier-4) or 56 MiB (tier-8).
// ---------------------------------------------------------------------------

typedef _Float16 half8 __attribute__((ext_vector_type(8)));  // MFMA A/B frag
typedef float f32x4  __attribute__((ext_vector_type(4)));    // MFMA C/D frag

typedef const __attribute__((address_space(1))) uint32_t* gas_ptr;
typedef __attribute__((address_space(3))) uint32_t* las_ptr;

__device__ __forceinline__ void gl_lds16(const void* g, void* l) {
    // async global->LDS, 16B/lane; LDS dest = wave-uniform base + lane*16
    __builtin_amdgcn_global_load_lds((gas_ptr)g, (las_ptr)l, 16, 0, 0);
}

#define L_ 2048
#define D_ 1024

// ---------------------------------------------------------------------------
// zero-fill d_out (atomics in k_pv accumulate into it)
// ---------------------------------------------------------------------------
__global__ __launch_bounds__(256) void k_zero(float* __restrict__ p, int n4) {
    const int i = blockIdx.x * 256 + threadIdx.x;
    if (i < n4) ((float4*)p)[i] = (float4){0.f, 0.f, 0.f, 0.f};
}

// ---------------------------------------------------------------------------
// transpose + cvt: dst[c][k] = fp16(src[k][c]).  src [R x C] fp32, dst [C x R].
// grid (R/64, C/64).
// ---------------------------------------------------------------------------
__global__ __launch_bounds__(256) void k_tcvt(
        const float* __restrict__ src, _Float16* __restrict__ dst, int C, int R) {
    __shared__ _Float16 tile[64][72];   // 144 B rows -> 16B-aligned
    const int k0 = blockIdx.x * 64, n0 = blockIdx.y * 64;
    const int t = threadIdx.x, row = t >> 2, cs = (t & 3) * 16;
    const float* sp = src + (size_t)(k0 + row) * C + n0 + cs;
#pragma unroll
    for (int q = 0; q < 4; q++) {
        float4 f = ((const float4*)sp)[q];
        tile[row][cs + q * 4 + 0] = (_Float16)f.x;
        tile[row][cs + q * 4 + 1] = (_Float16)f.y;
        tile[row][cs + q * 4 + 2] = (_Float16)f.z;
        tile[row][cs + q * 4 + 3] = (_Float16)f.w;
    }
    __syncthreads();
    union { _Float16 h[16]; uint4 q[2]; } pk;
#pragma unroll
    for (int j = 0; j < 16; j++) pk.h[j] = tile[cs + j][row];
    _Float16* dp = dst + (size_t)(n0 + row) * R + k0 + cs;
    *(uint4*)dp       = pk.q[0];
    *(uint4*)(dp + 8) = pk.q[1];
}

// ---------------------------------------------------------------------------
// G = W^T W  (fp16 out).  A = B = Wt (rows of W^T), 128x128 tile, BK=32.
// grid (8,8).
// ---------------------------------------------------------------------------
__global__ __launch_bounds__(256) void k_G(
        const _Float16* __restrict__ Wt, _Float16* __restrict__ Gf) {
    __shared__ _Float16 As[128 * 32], Bs[128 * 32];
    const int t = threadIdx.x, lane = t & 63, wave = t >> 6;
    const int quad = lane >> 4, l16 = lane & 15;
    const int wm = (wave >> 1) * 64, wn = (wave & 1) * 64;
    const int M0 = blockIdx.x * 128, N0 = blockIdx.y * 128;
    const int sr = wave * 32 + (lane >> 2), sc = (lane & 3) * 8;

    f32x4 acc[4][4];
#pragma unroll
    for (int i = 0; i < 4; i++)
#pragma unroll
        for (int j = 0; j < 4; j++) acc[i][j] = (f32x4){0.f, 0.f, 0.f, 0.f};

    for (int k0 = 0; k0 < D_; k0 += 32) {
        __syncthreads();
#pragma unroll
        for (int h = 0; h < 2; h++) {
            gl_lds16(Wt + (size_t)(M0 + sr + h * 16) * D_ + k0 + sc,
                     &As[(wave * 32 + h * 16) * 32]);
            gl_lds16(Wt + (size_t)(N0 + sr + h * 16) * D_ + k0 + sc,
                     &Bs[(wave * 32 + h * 16) * 32]);
        }
        __syncthreads();
        half8 a[4], b[4];
#pragma unroll
        for (int i = 0; i < 4; i++) a[i] = *(const half8*)&As[(wm + i * 16 + l16) * 32 + quad * 8];
#pragma unroll
        for (int j = 0; j < 4; j++) b[j] = *(const half8*)&Bs[(wn + j * 16 + l16) * 32 + quad * 8];
#pragma unroll
        for (int i = 0; i < 4; i++)
#pragma unroll
            for (int j = 0; j < 4; j++)
                acc[i][j] = __builtin_amdgcn_mfma_f32_16x16x32_f16(a[i], b[j], acc[i][j], 0, 0, 0);
    }
#pragma unroll
    for (int i = 0; i < 4; i++)
#pragma unroll
        for (int j = 0; j < 4; j++)
#pragma unroll
            for (int r = 0; r < 4; r++) {
                const int m = M0 + wm + i * 16 + quad * 4 + r;
                const int n = N0 + wn + j * 16 + l16;
                Gf[(size_t)m * D_ + n] = (_Float16)acc[i][j][r];
            }
}

// ---------------------------------------------------------------------------
// r[d] = sum_j W[j][d] * bias[j]   (zero when bias==0; kept for generality)
// ---------------------------------------------------------------------------
__global__ __launch_bounds__(256) void k_rvec(
        const float* __restrict__ W, const float* __restrict__ bias,
        float* __restrict__ rv) {
    const int d = blockIdx.x * 256 + threadIdx.x;
    float acc = 0.f;
    for (int j = 0; j < D_; j++) acc += W[(size_t)j * D_ + d] * bias[j];
    rv[d] = acc;
}

// ---------------------------------------------------------------------------
// t[n] = O[n] . r   (one wave per row)
// ---------------------------------------------------------------------------
__global__ __launch_bounds__(256) void k_tvec(
        const float* __restrict__ O, const float* __restrict__ rv,
        float* __restrict__ tv) {
    const int lane = threadIdx.x & 63, wave = threadIdx.x >> 6;
    const int row = blockIdx.x * 4 + wave;
    const float* op = O + (size_t)row * D_;
    float acc = 0.f;
#pragma unroll
    for (int it = 0; it < 4; it++) {
        const int d = (it * 64 + lane) * 4;
        float4 o = *(const float4*)(op + d);
        float4 r = *(const float4*)(rv + d);
        acc += o.x * r.x + o.y * r.y + o.z * r.z + o.w * r.w;
    }
#pragma unroll
    for (int o = 32; o > 0; o >>= 1) acc += __shfl_xor(acc, o, 64);
    if (lane == 0) tv[row] = acc;
}

// ---------------------------------------------------------------------------
// Y = X @ G  (fp16 out).  A = X fp32 (manual cvt stage), B = Gf (async).
// G symmetric so B rows of Gf give G[k][n].  grid (rows/128, 8).
// ---------------------------------------------------------------------------
__global__ __launch_bounds__(256) void k_Y(
        const float* __restrict__ X, const _Float16* __restrict__ Gf,
        _Float16* __restrict__ Y) {
    __shared__ _Float16 As[128 * 32], Bs[128 * 32];
    const int t = threadIdx.x, lane = t & 63, wave = t >> 6;
    const int quad = lane >> 4, l16 = lane & 15;
    const int wm = (wave >> 1) * 64, wn = (wave & 1) * 64;
    const int R0 = blockIdx.x * 128, N0 = blockIdx.y * 128;
    const int sr = wave * 32 + (lane >> 2), sc = (lane & 3) * 8;
    const int arow = t >> 1, acs = (t & 1) * 16;

    f32x4 acc[4][4];
#pragma unroll
    for (int i = 0; i < 4; i++)
#pragma unroll
        for (int j = 0; j < 4; j++) acc[i][j] = (f32x4){0.f, 0.f, 0.f, 0.f};

    for (int k0 = 0; k0 < D_; k0 += 32) {
        __syncthreads();
#pragma unroll
        for (int h = 0; h < 2; h++)
            gl_lds16(Gf + (size_t)(N0 + sr + h * 16) * D_ + k0 + sc,
                     &Bs[(wave * 32 + h * 16) * 32]);
        {
            const float* ap = X + (size_t)(R0 + arow) * D_ + k0 + acs;
            union { _Float16 h[16]; uint4 q[2]; } pk;
#pragma unroll
            for (int q = 0; q < 4; q++) {
                float4 f = ((const float4*)ap)[q];
                pk.h[q * 4 + 0] = (_Float16)f.x;
                pk.h[q * 4 + 1] = (_Float16)f.y;
                pk.h[q * 4 + 2] = (_Float16)f.z;
                pk.h[q * 4 + 3] = (_Float16)f.w;
            }
            *(uint4*)&As[arow * 32 + acs]     = pk.q[0];
            *(uint4*)&As[arow * 32 + acs + 8] = pk.q[1];
        }
        __syncthreads();
        half8 a[4], b[4];
#pragma unroll
        for (int i = 0; i < 4; i++) a[i] = *(const half8*)&As[(wm + i * 16 + l16) * 32 + quad * 8];
#pragma unroll
        for (int j = 0; j < 4; j++) b[j] = *(const half8*)&Bs[(wn + j * 16 + l16) * 32 + quad * 8];
#pragma unroll
        for (int i = 0; i < 4; i++)
#pragma unroll
            for (int j = 0; j < 4; j++)
                acc[i][j] = __builtin_amdgcn_mfma_f32_16x16x32_f16(a[i], b[j], acc[i][j], 0, 0, 0);
    }
#pragma unroll
    for (int i = 0; i < 4; i++)
#pragma unroll
        for (int j = 0; j < 4; j++)
#pragma unroll
            for (int r = 0; r < 4; r++) {
                const int m = R0 + wm + i * 16 + quad * 4 + r;
                const int n = N0 + wn + j * 16 + l16;
                Y[(size_t)m * D_ + n] = (_Float16)acc[i][j][r];
            }
}

// ---------------------------------------------------------------------------
// S = Y @ O^T + 1 t^T  (fp32 out).  A = Y fp16 (async), B = O fp32 (manual cvt).
// grid (16,16) per batch.
// ---------------------------------------------------------------------------
__global__ __launch_bounds__(256) void k_scores(
        const _Float16* __restrict__ Y, const float* __restrict__ O,
        const float* __restrict__ tv, float* __restrict__ S) {
    __shared__ _Float16 As[128 * 32], Bs[128 * 32];
    const int t = threadIdx.x, lane = t & 63, wave = t >> 6;
    const int quad = lane >> 4, l16 = lane & 15;
    const int wm = (wave >> 1) * 64, wn = (wave & 1) * 64;
    const int M0 = blockIdx.x * 128, N0 = blockIdx.y * 128;
    const int sr = wave * 32 + (lane >> 2), sc = (lane & 3) * 8;
    const int brow = t >> 1, bcs = (t & 1) * 16;

    f32x4 acc[4][4];
#pragma unroll
    for (int i = 0; i < 4; i++)
#pragma unroll
        for (int j = 0; j < 4; j++) acc[i][j] = (f32x4){0.f, 0.f, 0.f, 0.f};

    for (int k0 = 0; k0 < D_; k0 += 32) {
        __syncthreads();
#pragma unroll
        for (int h = 0; h < 2; h++)
            gl_lds16(Y + (size_t)(M0 + sr + h * 16) * D_ + k0 + sc,
                     &As[(wave * 32 + h * 16) * 32]);
        {
            const float* bp = O + (size_t)(N0 + brow) * D_ + k0 + bcs;
            union { _Float16 h[16]; uint4 q[2]; } pk;
#pragma unroll
            for (int q = 0; q < 4; q++) {
                float4 f = ((const float4*)bp)[q];
                pk.h[q * 4 + 0] = (_Float16)f.x;
                pk.h[q * 4 + 1] = (_Float16)f.y;
                pk.h[q * 4 + 2] = (_Float16)f.z;
                pk.h[q * 4 + 3] = (_Float16)f.w;
            }
            *(uint4*)&Bs[brow * 32 + bcs]     = pk.q[0];
            *(uint4*)&Bs[brow * 32 + bcs + 8] = pk.q[1];
        }
        __syncthreads();
        half8 a[4], b[4];
#pragma unroll
        for (int i = 0; i < 4; i++) a[i] = *(const half8*)&As[(wm + i * 16 + l16) * 32 + quad * 8];
#pragma unroll
        for (int j = 0; j < 4; j++) b[j] = *(const half8*)&Bs[(wn + j * 16 + l16) * 32 + quad * 8];
#pragma unroll
        for (int i = 0; i < 4; i++)
#pragma unroll
            for (int j = 0; j < 4; j++)
                acc[i][j] = __builtin_amdgcn_mfma_f32_16x16x32_f16(a[i], b[j], acc[i][j], 0, 0, 0);
    }
#pragma unroll
    for (int j = 0; j < 4; j++) {
        const int n = N0 + wn + j * 16 + l16;
        const float tn = tv[n];
#pragma unroll
        for (int i = 0; i < 4; i++)
#pragma unroll
            for (int r = 0; r < 4; r++) {
                const int m = M0 + wm + i * 16 + quad * 4 + r;
                S[(size_t)m * L_ + n] = acc[i][j][r] + tn;
            }
    }
}

// ---------------------------------------------------------------------------
// per-row max and 1/sum(exp) over 2048 cols.  grid = 2048 (one block/row).
// ---------------------------------------------------------------------------
__global__ __launch_bounds__(256) void k_rowstats(
        const float* __restrict__ S, float* __restrict__ rowM, float* __restrict__ rowInvL) {
    const size_t r = blockIdx.x;
    const float* row = S + r * (size_t)L_;
    const int t = threadIdx.x, lane = t & 63, wave = t >> 6;
    float4 v0 = ((const float4*)row)[t];
    float4 v1 = ((const float4*)row)[t + 256];
    float mx = fmaxf(fmaxf(fmaxf(v0.x, v0.y), fmaxf(v0.z, v0.w)),
                     fmaxf(fmaxf(v1.x, v1.y), fmaxf(v1.z, v1.w)));
#pragma unroll
    for (int o = 32; o > 0; o >>= 1) mx = fmaxf(mx, __shfl_xor(mx, o, 64));
    __shared__ float red[4];
    __shared__ float bmax;
    if (lane == 0) red[wave] = mx;
    __syncthreads();
    if (t == 0) bmax = fmaxf(fmaxf(red[0], red[1]), fmaxf(red[2], red[3]));
    __syncthreads();
    const float m = bmax;
    float s = __expf(fminf(v0.x - m, 0.f)) + __expf(fminf(v0.y - m, 0.f))
            + __expf(fminf(v0.z - m, 0.f)) + __expf(fminf(v0.w - m, 0.f))
            + __expf(fminf(v1.x - m, 0.f)) + __expf(fminf(v1.y - m, 0.f))
            + __expf(fminf(v1.z - m, 0.f)) + __expf(fminf(v1.w - m, 0.f));
#pragma unroll
    for (int o = 32; o > 0; o >>= 1) s += __shfl_xor(s, o, 64);
    __syncthreads();
    if (lane == 0) red[wave] = s;
    __syncthreads();
    if (t == 0) {
        rowM[r] = m;
        rowInvL[r] = 1.0f / (red[0] + red[1] + red[2] + red[3]);
    }
}

// ---------------------------------------------------------------------------
// out += P @ V  (K-split z=2, fp32 atomicAdd into zeroed out).
// A = P fp16 from S (manual: exp+cvt), B = Vt fp16 (async).
// grid (16, 8, 2) per batch.
// ---------------------------------------------------------------------------
__global__ __launch_bounds__(256) void k_pv(
        const float* __restrict__ S, const float* __restrict__ rowM,
        const float* __restrict__ rowInvL, const _Float16* __restrict__ Vt,
        float* __restrict__ out) {
    __shared__ _Float16 Ps[128 * 32], Vs[128 * 32];
    const int t = threadIdx.x, lane = t & 63, wave = t >> 6;
    const int quad = lane >> 4, l16 = lane & 15;
    const int wm = (wave >> 1) * 64, wn = (wave & 1) * 64;
    const int M0 = blockIdx.x * 128, N0 = blockIdx.y * 128;
    const int kz = blockIdx.z * 1024;
    const int sr = wave * 32 + (lane >> 2), sc = (lane & 3) * 8;
    const int prow = t >> 1, pcs = (t & 1) * 16;
    const float rm = rowM[M0 + prow], ril = rowInvL[M0 + prow];
    const float* sp0 = S + (size_t)(M0 + prow) * L_ + kz + pcs;

    f32x4 acc[4][4];
#pragma unroll
    for (int i = 0; i < 4; i++)
#pragma unroll
        for (int j = 0; j < 4; j++) acc[i][j] = (f32x4){0.f, 0.f, 0.f, 0.f};

    for (int k0 = 0; k0 < 1024; k0 += 32) {
        __syncthreads();
#pragma unroll
        for (int h = 0; h < 2; h++)
            gl_lds16(Vt + (size_t)(N0 + sr + h * 16) * L_ + kz + k0 + sc,
                     &Vs[(wave * 32 + h * 16) * 32]);
        {
            const float4* sp = (const float4*)(sp0 + k0);
            union { _Float16 h[16]; uint4 q[2]; } pk;
#pragma unroll
            for (int q = 0; q < 4; q++) {
                float4 f = sp[q];
                pk.h[q * 4 + 0] = (_Float16)(__expf(fminf(f.x - rm, 0.f)) * ril);
                pk.h[q * 4 + 1] = (_Float16)(__expf(fminf(f.y - rm, 0.f)) * ril);
                pk.h[q * 4 + 2] = (_Float16)(__expf(fminf(f.z - rm, 0.f)) * ril);
                pk.h[q * 4 + 3] = (_Float16)(__expf(fminf(f.w - rm, 0.f)) * ril);
            }
            *(uint4*)&Ps[prow * 32 + pcs]     = pk.q[0];
            *(uint4*)&Ps[prow * 32 + pcs + 8] = pk.q[1];
        }
        __syncthreads();
        half8 a[4], b[4];
#pragma unroll
        for (int i = 0; i < 4; i++) a[i] = *(const half8*)&Ps[(wm + i * 16 + l16) * 32 + quad * 8];
#pragma unroll
        for (int j = 0; j < 4; j++) b[j] = *(const half8*)&Vs[(wn + j * 16 + l16) * 32 + quad * 8];
#pragma unroll
        for (int i = 0; i < 4; i++)
#pragma unroll
            for (int j = 0; j < 4; j++)
                acc[i][j] = __builtin_amdgcn_mfma_f32_16x16x32_f16(a[i], b[j], acc[i][j], 0, 0, 0);
    }
#pragma unroll
    for (int i = 0; i < 4; i++)
#pragma unroll
        for (int j = 0; j < 4; j++)
#pragma unroll
            for (int r = 0; r < 4; r++) {
                const int m = M0 + wm + i * 16 + quad * 4 + r;
                const int n = N0 + wn + j * 16 + l16;
                atomicAdd(&out[(size_t)m * D_ + n], acc[i][j][r]);
            }
}

// ---------------------------------------------------------------------------
extern "C" void kernel_launch(void* const* d_in, const int* in_sizes, int n_in,
                              void* d_out, int out_size, void* d_ws, size_t ws_size,
                              hipStream_t stream) {
    const float* ix   = (const float*)d_in[0];
    const float* io   = (const float*)d_in[1];
    const float* W    = (const float*)d_in[2];
    const float* bias = (const float*)d_in[3];
    float* out = (float*)d_out;

    const size_t MB = 1024 * 1024;
    // tier: Y buffer holds nY batches (8 if ws allows, else 4)
    const int nY = (ws_size >= 59 * MB) ? 8 : 4;

    char* ws = (char*)d_ws;
    _Float16* Wt = (_Float16*)ws;                       // 2 MiB  (dead after k_G)
    float* rv    = (float*)ws;                          // 4 KiB  (aliases dead Wt)
    float* tv    = (float*)(ws + 4096);                 // 8 KiB
    float* rowM  = (float*)(ws + 12288);                // 8 KiB
    float* rowL  = (float*)(ws + 20480);                // 8 KiB
    _Float16* Gf = (_Float16*)(ws + 2 * MB);            // 2 MiB
    _Float16* Yb = (_Float16*)(ws + 4 * MB);            // nY * 4 MiB
    _Float16* Vt = (_Float16*)(ws + (4 + 4 * (size_t)nY) * MB);   // 4 MiB
    float* S     = (float*)(ws + (8 + 4 * (size_t)nY) * MB);      // 16 MiB
    // total: 24 + 4*nY MiB  (40 MiB tier-4, 56 MiB tier-8)

    k_zero<<<16384, 256, 0, stream>>>(out, (8 * L_ * D_) / 4);
    k_tcvt<<<dim3(16, 16), 256, 0, stream>>>(W, Wt, D_, D_);      // Wt = fp16(W^T)
    k_G<<<dim3(8, 8), 256, 0, stream>>>(Wt, Gf);                  // G = W^T W
    k_rvec<<<4, 256, 0, stream>>>(W, bias, rv);                   // r = W^T b

    for (int q = 0; q < 8 / nY; q++) {
        k_Y<<<dim3(nY * 16, 8), 256, 0, stream>>>(ix + (size_t)q * nY * L_ * D_, Gf, Yb);
        for (int j = 0; j < nY; j++) {
            const int b = q * nY + j;
            const float* Ob = io + (size_t)b * L_ * D_;
            k_tvec<<<512, 256, 0, stream>>>(Ob, rv, tv);          // t = O r
            k_tcvt<<<dim3(32, 16), 256, 0, stream>>>(Ob, Vt, D_, L_);  // Vt = fp16(O^T)
            k_scores<<<dim3(16, 16), 256, 0, stream>>>(Yb + (size_t)j * L_ * D_, Ob, tv, S);
            k_rowstats<<<2048, 256, 0, stream>>>(S, rowM, rowL);
            k_pv<<<dim3(16, 8, 2), 256, 0, stream>>>(S, rowM, rowL, Vt,
                                                     out + (size_t)b * L_ * D_);
        }
    }
}